// Round 2
// baseline (32.102 us; speedup 1.0000x reference)
//
#include <hip/hip_runtime.h>
#include <hip/hip_bf16.h>

// out[b,o] = sum_{i,n} T_n(x[b,i]) * w[o,i,n]
// GEMM view: M=B=65536, N=O=32, K=I*8=2048, k = i*8+n.
// MFMA: v_mfma_f32_32x32x16_bf16, K-chunk 16 = one i-pair (kc2 = 0..127).

typedef __attribute__((ext_vector_type(8)))  short bf16x8;
typedef __attribute__((ext_vector_type(16))) float f32x16;
typedef __attribute__((ext_vector_type(4)))  float f32x4;

__device__ __forceinline__ short f2b(float f) {
    __hip_bfloat16 h = __float2bfloat16(f);
    short s;
    __builtin_memcpy(&s, &h, sizeof(s));
    return s;
}

// Pack w [32][256][8] fp32 -> wB[kc2][lane][jj] bf16 in B-fragment order:
//   o = lane&31, g = lane>>5, i = 2*kc2 + (jj>>2), n = 4*g + (jj&3)
__global__ __launch_bounds__(256) void prep_w_kernel(const float* __restrict__ w,
                                                     short* __restrict__ wB) {
    int idx = blockIdx.x * 256 + threadIdx.x;     // 0..65535
    int kc2 = idx >> 9;
    int l   = (idx >> 3) & 63;
    int jj  = idx & 7;
    int o = l & 31, g = l >> 5;
    int i = 2 * kc2 + (jj >> 2);
    int n = 4 * g + (jj & 3);
    wB[idx] = f2b(w[(o * 256 + i) * 8 + n]);
}

// Block: 256 thr = 4 waves, 64 rows of x. Waves split K 4 ways (32 kc2 each).
// Each wave: 2 row-tiles of 32 rows, acc = 2 x f32x16. LDS-reduce at the end.
__global__ __launch_bounds__(256) void cheb_mm_kernel(const float* __restrict__ x,
                                                      const short* __restrict__ wB,
                                                      float* __restrict__ out) {
    __shared__ float smem[16384];                 // 64 KB: x-stage, then partials
    const int tid = threadIdx.x;
    const int wv  = tid >> 6;
    const int l   = tid & 63;
    const int g   = l >> 5;                       // lane half (n-half selector)
    const int r0  = l & 31;                       // row within 32-row tile / o col
    const long long row0 = (long long)blockIdx.x * 64;

    // ---- stage x[64][256] -> LDS as float2 pairs, XOR-swizzled pair index ----
    {
        const float2* xg = (const float2*)x + row0 * 128;
        float2* s2 = (float2*)smem;
        #pragma unroll
        for (int it = 0; it < 32; ++it) {
            int f = it * 256 + tid;               // 0..8191 (coalesced)
            int r = f >> 7, p = f & 127;
            float2 v = xg[f];
            s2[r * 128 + (p ^ (r & 15))] = v;
        }
    }
    __syncthreads();

    f32x16 acc0{};
    f32x16 acc1{};
    const float2* s2 = (const float2*)smem;
    const bf16x8* wBv = (const bf16x8*)wB;

    #pragma unroll 4
    for (int t = 0; t < 32; ++t) {
        const int kc2 = wv * 32 + t;              // this wave's K range
        const bf16x8 bfrag = wBv[kc2 * 64 + l];   // coalesced 16B, L2-resident
        #pragma unroll
        for (int rt = 0; rt < 2; ++rt) {
            const int row = rt * 32 + r0;
            const float2 xv = s2[row * 128 + (kc2 ^ (row & 15))];
            const float xa = xv.x, xb = xv.y;
            const float x2a = xa + xa, x2b = xb + xb;
            // Chebyshev T2..T5 (fp32)
            const float a2 = x2a * xa - 1.f;
            const float a3 = x2a * a2 - xa;
            const float a4 = x2a * a3 - a2;
            const float a5 = x2a * a4 - a3;
            const float b2 = x2b * xb - 1.f;
            const float b3 = x2b * b2 - xb;
            const float b4 = x2b * b3 - b2;
            const float b5 = x2b * b4 - b3;
            // lane half g picks T_{4g..4g+3}; recurrence extends any pair
            const float ua0 = g ? a4 : 1.f;
            const float ua1 = g ? a5 : xa;
            const float ua2 = x2a * ua1 - ua0;    // T6 or T2
            const float ua3 = x2a * ua2 - ua1;    // T7 or T3
            const float ub0 = g ? b4 : 1.f;
            const float ub1 = g ? b5 : xb;
            const float ub2 = x2b * ub1 - ub0;
            const float ub3 = x2b * ub2 - ub1;
            bf16x8 afrag;
            afrag[0] = f2b(ua0); afrag[1] = f2b(ua1);
            afrag[2] = f2b(ua2); afrag[3] = f2b(ua3);
            afrag[4] = f2b(ub0); afrag[5] = f2b(ub1);
            afrag[6] = f2b(ub2); afrag[7] = f2b(ub3);
            if (rt == 0)
                acc0 = __builtin_amdgcn_mfma_f32_32x32x16_bf16(afrag, bfrag, acc0, 0, 0, 0);
            else
                acc1 = __builtin_amdgcn_mfma_f32_32x32x16_bf16(afrag, bfrag, acc1, 0, 0, 0);
        }
    }

    __syncthreads();                              // done reading x; reuse LDS
    // partials[wv][64][32]: C/D layout col=lane&31, row=(r&3)+8*(r>>2)+4*g
    #pragma unroll
    for (int rt = 0; rt < 2; ++rt) {
        const f32x16 a = rt ? acc1 : acc0;
        #pragma unroll
        for (int r = 0; r < 16; ++r) {
            const int rloc = (r & 3) + 8 * (r >> 2) + 4 * g;
            smem[wv * 2048 + (rt * 32 + rloc) * 32 + r0] = a[r];
        }
    }
    __syncthreads();

    // reduce 4 partials, coalesced f32x4 store of out[64][32] block
    {
        float* op = out + row0 * 32;
        #pragma unroll
        for (int h = 0; h < 2; ++h) {
            const int f = tid * 8 + h * 4;
            f32x4 v0 = *(const f32x4*)&smem[f];
            f32x4 v1 = *(const f32x4*)&smem[2048 + f];
            f32x4 v2 = *(const f32x4*)&smem[4096 + f];
            f32x4 v3 = *(const f32x4*)&smem[6144 + f];
            f32x4 s = (v0 + v1) + (v2 + v3);
            *(f32x4*)(op + f) = s;
        }
    }
}

extern "C" void kernel_launch(void* const* d_in, const int* in_sizes, int n_in,
                              void* d_out, int out_size, void* d_ws, size_t ws_size,
                              hipStream_t stream) {
    const float* x = (const float*)d_in[0];   // [65536, 256] fp32
    const float* w = (const float*)d_in[1];   // [32, 256, 8] fp32
    float* out = (float*)d_out;               // [65536, 32] fp32
    short* wB = (short*)d_ws;                 // 128 KB bf16 packed weights

    prep_w_kernel<<<256, 256, 0, stream>>>(w, wB);
    cheb_mm_kernel<<<1024, 256, 0, stream>>>(x, wB, out);
}